// Round 17
// baseline (229.043 us; speedup 1.0000x reference)
//
#include <hip/hip_runtime.h>
#include <hip/hip_bf16.h>

#define NPIX 4096
#define SCALE_L2E 0.18033688f   // 0.125 * log2(e); folded into Wq cast

typedef unsigned short ushort_t;
typedef __attribute__((ext_vector_type(8))) short bf16x8;
typedef __attribute__((ext_vector_type(4))) float f32x4;
typedef __attribute__((ext_vector_type(8))) unsigned short us8;

__device__ __forceinline__ float bf2f(ushort_t u) {
  union { unsigned int i; float f; } v; v.i = ((unsigned int)u) << 16; return v.f;
}
__device__ __forceinline__ ushort_t f2bf(float f) {
  union { float f; unsigned int i; } v; v.f = f;
  unsigned int r = v.i + 0x7fffu + ((v.i >> 16) & 1u);
  return (ushort_t)(r >> 16);
}
__device__ __forceinline__ unsigned int cvtpk(float lo, float hi) {
  unsigned int r;
  asm volatile("v_cvt_pk_bf16_f32 %0, %1, %2" : "=v"(r) : "v"(lo), "v"(hi));
  return r;
}

__device__ __forceinline__ void gload16(const void* g, void* l) {
  __builtin_amdgcn_global_load_lds(
      (const __attribute__((address_space(1))) void*)g,
      (__attribute__((address_space(3))) void*)l, 16, 0, 0);
}

#define VMW(N) asm volatile("s_waitcnt vmcnt(" #N ")" ::: "memory")
#define BARRS do { __builtin_amdgcn_s_barrier(); \
                   __builtin_amdgcn_sched_barrier(0); } while (0)

// ---------------------------------------------------------------------------
// Fused weight prep: 4 segments of 512x512 f32 -> bf16.
// ---------------------------------------------------------------------------
__global__ __launch_bounds__(256) void prep_w(const float* __restrict__ wqk,
                                              const float* __restrict__ wv,
                                              const float* __restrict__ wproj,
                                              ushort_t* __restrict__ WQKV,
                                              ushort_t* __restrict__ WPb) {
  const int i = (blockIdx.x * 256 + threadIdx.x) * 4;
  const int seg = i >> 18, off = i & 262143;
  const float* src;
  ushort_t* dst;
  float sc = 1.0f;
  if (seg == 0)      { src = wqk;          dst = WQKV;               sc = SCALE_L2E; }
  else if (seg == 1) { src = wqk + 262144; dst = WQKV + 262144; }
  else if (seg == 2) { src = wv;           dst = WQKV + 2 * 262144; }
  else               { src = wproj;        dst = WPb; }
  const float4 v = *(const float4*)&src[off];
  ushort4 o = make_ushort4(f2bf(v.x * sc), f2bf(v.y * sc),
                           f2bf(v.z * sc), f2bf(v.w * sc));
  *(ushort4*)&dst[off] = o;
}

// ---------------------------------------------------------------------------
// W_lepe[i][j] = sum_c w_v_vert[i][c] * w_v[256+c][j]   (256x512, bf16 out)
// ---------------------------------------------------------------------------
__global__ __launch_bounds__(256) void lepe_w(const float* __restrict__ wvv,
                                              const float* __restrict__ wv,
                                              ushort_t* __restrict__ out) {
  const int i = blockIdx.x, tid = threadIdx.x;
  float a0 = 0.f, a1 = 0.f;
  for (int c = 0; c < 256; ++c) {
    const float wc = wvv[i * 256 + c];
    a0 = fmaf(wc, wv[(size_t)(256 + c) * 512 + tid], a0);
    a1 = fmaf(wc, wv[(size_t)(256 + c) * 512 + 256 + tid], a1);
  }
  out[(size_t)i * 512 + tid] = f2bf(a0);
  out[(size_t)i * 512 + 256 + tid] = f2bf(a1);
}

// ---------------------------------------------------------------------------
// fmap [b][512][4096] f32 -> XT [b][4096][512] bf16 (float4 reads).
// ---------------------------------------------------------------------------
__global__ __launch_bounds__(256) void transpose_cast(const float* __restrict__ fmap,
                                                      ushort_t* __restrict__ XT) {
  const int b = blockIdx.z, p0 = blockIdx.x * 64, c0 = blockIdx.y * 64;
  const int tid = threadIdx.x;
  __shared__ float t[64][65];
  const float* src = fmap + ((size_t)b * 512 + c0) * NPIX + p0;
  const int cr = tid >> 4;
  const int p4 = (tid & 15) * 4;
  #pragma unroll
  for (int i = 0; i < 4; ++i) {
    const int c = i * 16 + cr;
    const float4 v = *(const float4*)&src[(size_t)c * NPIX + p4];
    t[c][p4 + 0] = v.x; t[c][p4 + 1] = v.y;
    t[c][p4 + 2] = v.z; t[c][p4 + 3] = v.w;
  }
  __syncthreads();
  const int pw = tid >> 2, cwb = (tid & 3) * 16;
  us8 o0, o1;
  #pragma unroll
  for (int i = 0; i < 8; ++i) o0[i] = f2bf(t[cwb + i][pw]);
  #pragma unroll
  for (int i = 0; i < 8; ++i) o1[i] = f2bf(t[cwb + 8 + i][pw]);
  ushort_t* dst = XT + ((size_t)b * NPIX + p0 + pw) * 512 + c0 + cwb;
  *(us8*)&dst[0] = o0;
  *(us8*)&dst[8] = o1;
}

// ---------------------------------------------------------------------------
// QKV GEMM (r16, unchanged): 128(M) x 256(N) tile, BK=32, per-wave 64x128,
// 3-buffer rotation (72 KB, 2 blocks/CU), counted VMW(6).
// ---------------------------------------------------------------------------
__global__ __launch_bounds__(256, 2) void gemm_qkv(
    const ushort_t* __restrict__ A, const ushort_t* __restrict__ B,
    ushort_t* __restrict__ qkT, ushort_t* __restrict__ vbuf)
{
  const int b = blockIdx.z;
  const int p0 = blockIdx.x * 256;
  const int o0 = blockIdx.y * 128;
  const int tid = threadIdx.x;
  const int lane = tid & 63, w = tid >> 6;
  const int wrow = (w >> 1) * 64;
  const int wcol = (w & 1) * 128;
  const int g = lane >> 4, q16 = lane & 15;

  __shared__ __attribute__((aligned(16))) ushort_t lds[3 * 12288];

  const ushort_t* Bb = B + (size_t)b * NPIX * 512;

  f32x4 acc[4][8];
  #pragma unroll
  for (int m = 0; m < 4; ++m)
    #pragma unroll
    for (int n = 0; n < 8; ++n) acc[m][n] = (f32x4){0.f, 0.f, 0.f, 0.f};

  auto Ap = [&](int buf) { return lds + buf * 12288; };
  auto Bp = [&](int buf) { return lds + buf * 12288 + 4096; };

  auto stage = [&](int buf, int kb) {
    #pragma unroll
    for (int i = 0; i < 2; ++i) {
      const int r = w * 32 + i * 16 + (lane >> 2);
      const int cs = (lane & 3) ^ ((r >> 1) & 3);
      gload16(&A[(size_t)(o0 + r) * 512 + kb + cs * 8], Ap(buf) + (w * 32 + i * 16) * 32);
    }
    #pragma unroll
    for (int i = 0; i < 4; ++i) {
      const int r = w * 64 + i * 16 + (lane >> 2);
      const int cs = (lane & 3) ^ ((r >> 1) & 3);
      gload16(&Bb[(size_t)(p0 + r) * 512 + kb + cs * 8], Bp(buf) + (w * 64 + i * 16) * 32);
    }
  };

  stage(0, 0);
  stage(1, 32);
  VMW(6);
  BARRS;

  #pragma unroll 1
  for (int kt = 0; kt < 16; ++kt) {
    const int c = kt % 3;
    if (kt < 14) stage((kt + 2) % 3, (kt + 2) * 32);
    bf16x8 af[4], bfr[8];
    #pragma unroll
    for (int m = 0; m < 4; ++m) {
      const int rr = wrow + m * 16 + q16;
      af[m] = *(const bf16x8*)&Ap(c)[rr * 32 + (g ^ ((rr >> 1) & 3)) * 8];
    }
    #pragma unroll
    for (int n = 0; n < 8; ++n) {
      const int rr = wcol + n * 16 + q16;
      bfr[n] = *(const bf16x8*)&Bp(c)[rr * 32 + (g ^ ((rr >> 1) & 3)) * 8];
    }
    __builtin_amdgcn_s_setprio(1);
    #pragma unroll
    for (int m = 0; m < 4; ++m)
      #pragma unroll
      for (int n = 0; n < 8; ++n)
        acc[m][n] = __builtin_amdgcn_mfma_f32_16x16x32_bf16(af[m], bfr[n], acc[m][n], 0, 0, 0);
    __builtin_amdgcn_s_setprio(0);
    if (kt < 14) { VMW(6); BARRS; }
    else if (kt == 14) { VMW(0); BARRS; }
  }

  const int fr = lane & 15, fq = lane >> 4;
  if (o0 < 1024) {
    ushort_t* CT = qkT + (size_t)b * NPIX * 1024;
    #pragma unroll
    for (int m = 0; m < 4; ++m)
      #pragma unroll
      for (int n = 0; n < 8; ++n) {
        const int pix = p0 + wcol + n * 16 + fr;
        const int chb = o0 + wrow + m * 16 + fq * 4;
        ushort4 s4 = make_ushort4(f2bf(acc[m][n][0]), f2bf(acc[m][n][1]),
                                  f2bf(acc[m][n][2]), f2bf(acc[m][n][3]));
        *(ushort4*)&CT[(size_t)pix * 1024 + chb] = s4;
      }
  } else {
    ushort_t* C = vbuf + (size_t)b * 768 * NPIX;
    #pragma unroll
    for (int m = 0; m < 4; ++m)
      #pragma unroll
      for (int n = 0; n < 8; ++n) {
        const int col = p0 + wcol + n * 16 + fr;
        #pragma unroll
        for (int j = 0; j < 4; ++j) {
          const int row = o0 - 1024 + wrow + m * 16 + fq * 4 + j;
          C[(size_t)row * NPIX + col] = f2bf(acc[m][n][j]);
        }
      }
  }
}

// ---------------------------------------------------------------------------
// proj GEMM: 128(M) x 256(N) tile -> grid (16,4,8) = 512 blocks = 2/CU =
// EXACTLY one dispatch round (was 1024 blocks at 3/CU = 1.33 rounds with a
// quarter-occupancy tail). Same skeleton as gemm_qkv; f32+residual epilogue.
// ---------------------------------------------------------------------------
__global__ __launch_bounds__(256, 2) void gemm_proj(
    const ushort_t* __restrict__ A, const ushort_t* __restrict__ B,
    float* __restrict__ outF, const float* __restrict__ Res)
{
  const int b = blockIdx.z;
  const int p0 = blockIdx.x * 256;
  const int o0 = blockIdx.y * 128;
  const int tid = threadIdx.x;
  const int lane = tid & 63, w = tid >> 6;
  const int wrow = (w >> 1) * 64;
  const int wcol = (w & 1) * 128;
  const int g = lane >> 4, q16 = lane & 15;

  __shared__ __attribute__((aligned(16))) ushort_t lds[3 * 12288];

  const ushort_t* Bb = B + (size_t)b * NPIX * 512;

  f32x4 acc[4][8];
  #pragma unroll
  for (int m = 0; m < 4; ++m)
    #pragma unroll
    for (int n = 0; n < 8; ++n) acc[m][n] = (f32x4){0.f, 0.f, 0.f, 0.f};

  auto Ap = [&](int buf) { return lds + buf * 12288; };
  auto Bp = [&](int buf) { return lds + buf * 12288 + 4096; };

  auto stage = [&](int buf, int kb) {
    #pragma unroll
    for (int i = 0; i < 2; ++i) {
      const int r = w * 32 + i * 16 + (lane >> 2);
      const int cs = (lane & 3) ^ ((r >> 1) & 3);
      gload16(&A[(size_t)(o0 + r) * 512 + kb + cs * 8], Ap(buf) + (w * 32 + i * 16) * 32);
    }
    #pragma unroll
    for (int i = 0; i < 4; ++i) {
      const int r = w * 64 + i * 16 + (lane >> 2);
      const int cs = (lane & 3) ^ ((r >> 1) & 3);
      gload16(&Bb[(size_t)(p0 + r) * 512 + kb + cs * 8], Bp(buf) + (w * 64 + i * 16) * 32);
    }
  };

  stage(0, 0);
  stage(1, 32);
  VMW(6);
  BARRS;

  #pragma unroll 1
  for (int kt = 0; kt < 16; ++kt) {
    const int c = kt % 3;
    if (kt < 14) stage((kt + 2) % 3, (kt + 2) * 32);
    bf16x8 af[4], bfr[8];
    #pragma unroll
    for (int m = 0; m < 4; ++m) {
      const int rr = wrow + m * 16 + q16;
      af[m] = *(const bf16x8*)&Ap(c)[rr * 32 + (g ^ ((rr >> 1) & 3)) * 8];
    }
    #pragma unroll
    for (int n = 0; n < 8; ++n) {
      const int rr = wcol + n * 16 + q16;
      bfr[n] = *(const bf16x8*)&Bp(c)[rr * 32 + (g ^ ((rr >> 1) & 3)) * 8];
    }
    __builtin_amdgcn_s_setprio(1);
    #pragma unroll
    for (int m = 0; m < 4; ++m)
      #pragma unroll
      for (int n = 0; n < 8; ++n)
        acc[m][n] = __builtin_amdgcn_mfma_f32_16x16x32_bf16(af[m], bfr[n], acc[m][n], 0, 0, 0);
    __builtin_amdgcn_s_setprio(0);
    if (kt < 14) { VMW(6); BARRS; }
    else if (kt == 14) { VMW(0); BARRS; }
  }

  const int fr = lane & 15, fq = lane >> 4;
  float* C = outF + (size_t)b * 512 * NPIX;
  const float* R = Res + (size_t)b * 512 * NPIX;
  #pragma unroll
  for (int m = 0; m < 4; ++m)
    #pragma unroll
    for (int n = 0; n < 8; ++n) {
      const int col = p0 + wcol + n * 16 + fr;
      #pragma unroll
      for (int j = 0; j < 4; ++j) {
        const int row = o0 + wrow + m * 16 + fq * 4 + j;
        const size_t idx = (size_t)row * NPIX + col;
        C[idx] = acc[m][n][j] + R[idx];
      }
    }
}

// ---------------------------------------------------------------------------
// MFMA flash attention (r14 version, unchanged).
// ---------------------------------------------------------------------------
__global__ __launch_bounds__(256) void attn_mfma(const ushort_t* __restrict__ qkT,
                                                 const ushort_t* __restrict__ vbuf,
                                                 ushort_t* __restrict__ attT) {
  const int hh = blockIdx.x, wi = blockIdx.y, vert = blockIdx.z;
  const int b = wi >> 4, iw = wi & 15;
  const int tid = threadIdx.x;
  const int lane = tid & 63, w = tid >> 6;
  const int g = lane >> 4, q16 = lane & 15;
  const int qbase = w * 64;

  __shared__ __attribute__((aligned(16))) ushort_t K_lds[256 * 32];
  __shared__ __attribute__((aligned(16))) ushort_t VT_lds[32 * 256];
  __shared__ __attribute__((aligned(16))) ushort_t P_lds[4][64 * 40];

  const ushort_t* QKb = qkT + (size_t)b * NPIX * 1024;

  #pragma unroll
  for (int it = 0; it < 4; ++it) {
    const int j = w * 64 + it * 16 + (lane >> 2);
    const int cs = (lane & 3) ^ ((j >> 1) & 3);
    const int pj = vert ? iw * 256 + j : (j >> 2) * 64 + iw * 4 + (j & 3);
    gload16(&QKb[(size_t)pj * 1024 + 512 + hh * 32 + cs * 8],
            &K_lds[(w * 64 + it * 16) * 32]);
  }
  const ushort_t* Vg = vbuf + ((size_t)b * 768 + vert * 256 + hh * 32) * (size_t)NPIX;
  #pragma unroll
  for (int it = 0; it < 8; ++it) {
    const int d = it * 4 + w;
    const int jg = lane;
    const int pb = vert ? iw * 256 + jg * 4 : jg * 64 + iw * 4;
    const ushort4 v4 = *(const ushort4*)&Vg[(size_t)d * NPIX + pb];
    *(ushort4*)&VT_lds[d * 256 + (((jg >> 1) ^ d) << 3) + ((jg & 1) << 2)] = v4;
  }
  bf16x8 qf[4];
  #pragma unroll
  for (int qt = 0; qt < 4; ++qt) {
    const int q = qbase + qt * 16 + q16;
    const int qp = vert ? iw * 256 + q : (q >> 2) * 64 + iw * 4 + (q & 3);
    qf[qt] = *(const bf16x8*)&QKb[(size_t)qp * 1024 + hh * 32 + g * 8];
  }
  __syncthreads();

  float l[4] = {0.f, 0.f, 0.f, 0.f};
  f32x4 o[4][2];
  #pragma unroll
  for (int qt = 0; qt < 4; ++qt) {
    o[qt][0] = (f32x4){0.f, 0.f, 0.f, 0.f};
    o[qt][1] = (f32x4){0.f, 0.f, 0.f, 0.f};
  }

  const f32x4 zero4 = (f32x4){0.f, 0.f, 0.f, 0.f};
  const int kc = g ^ ((q16 >> 1) & 3);

  for (int jc = 0; jc < 8; ++jc) {
    bf16x8 kf0 = *(const bf16x8*)&K_lds[(jc * 32 + q16) * 32 + kc * 8];
    bf16x8 kf1 = *(const bf16x8*)&K_lds[(jc * 32 + 16 + q16) * 32 + kc * 8];
    f32x4 st[2][4];
    #pragma unroll
    for (int qt = 0; qt < 4; ++qt) {
      st[0][qt] = __builtin_amdgcn_mfma_f32_16x16x32_bf16(kf0, qf[qt], zero4, 0, 0, 0);
      st[1][qt] = __builtin_amdgcn_mfma_f32_16x16x32_bf16(kf1, qf[qt], zero4, 0, 0, 0);
    }
    #pragma unroll
    for (int qt = 0; qt < 4; ++qt) {
      const float p00 = exp2f(st[0][qt][0]), p01 = exp2f(st[0][qt][1]);
      const float p02 = exp2f(st[0][qt][2]), p03 = exp2f(st[0][qt][3]);
      const float p10 = exp2f(st[1][qt][0]), p11 = exp2f(st[1][qt][1]);
      const float p12 = exp2f(st[1][qt][2]), p13 = exp2f(st[1][qt][3]);
      float rs = ((p00 + p01) + (p02 + p03)) + ((p10 + p11) + (p12 + p13));
      rs += __shfl_xor(rs, 16);
      rs += __shfl_xor(rs, 32);
      l[qt] += rs;
      uint2 pk0, pk1;
      pk0.x = cvtpk(p00, p01); pk0.y = cvtpk(p02, p03);
      pk1.x = cvtpk(p10, p11); pk1.y = cvtpk(p12, p13);
      *(uint2*)&P_lds[w][(qt * 16 + q16) * 40 + g * 4]      = pk0;
      *(uint2*)&P_lds[w][(qt * 16 + q16) * 40 + 16 + g * 4] = pk1;
    }
    const int vc0 = (jc * 4 + g) ^ q16;
    const int vc1 = (jc * 4 + g) ^ (16 + q16);
    bf16x8 vf0 = *(const bf16x8*)&VT_lds[q16 * 256 + vc0 * 8];
    bf16x8 vf1 = *(const bf16x8*)&VT_lds[(16 + q16) * 256 + vc1 * 8];
    #pragma unroll
    for (int qt = 0; qt < 4; ++qt) {
      bf16x8 pf = *(const bf16x8*)&P_lds[w][(qt * 16 + q16) * 40 + g * 8];
      o[qt][0] = __builtin_amdgcn_mfma_f32_16x16x32_bf16(pf, vf0, o[qt][0], 0, 0, 0);
      o[qt][1] = __builtin_amdgcn_mfma_f32_16x16x32_bf16(pf, vf1, o[qt][1], 0, 0, 0);
    }
  }

  if (vert) {
    __syncthreads();
    const ushort_t* Lg = vbuf + ((size_t)b * 768 + 512 + hh * 32) * (size_t)NPIX;
    #pragma unroll
    for (int it = 0; it < 8; ++it) {
      const int d = it * 4 + w;
      const int jg = lane;
      const ushort4 l4 = *(const ushort4*)&Lg[(size_t)d * NPIX + iw * 256 + jg * 4];
      *(ushort4*)&K_lds[d * 256 + (((jg >> 1) ^ d) << 3) + ((jg & 1) << 2)] = l4;
    }
    __syncthreads();
  }

  const int ch = vert * 256 + hh * 32;
  #pragma unroll
  for (int qt = 0; qt < 4; ++qt) {
    const float linv = 1.f / l[qt];
    float li[4];
    #pragma unroll
    for (int jj = 0; jj < 4; ++jj) li[jj] = __shfl(linv, g * 4 + jj);
    #pragma unroll
    for (int dt = 0; dt < 2; ++dt) {
      const int d = dt * 16 + q16;
      #pragma unroll
      for (int jj = 0; jj < 4; ++jj) {
        const int q = qbase + qt * 16 + g * 4 + jj;
        const int sw = d * 256 + (((q >> 3) ^ d) << 3) + (q & 7);
        const float lep = vert ? bf2f(K_lds[sw]) : bf2f(VT_lds[sw]);
        const int pix = vert ? iw * 256 + q : (q >> 2) * 64 + iw * 4 + (q & 3);
        attT[((size_t)b * NPIX + pix) * 512 + ch + d] = f2bf(o[qt][dt][jj] * li[jj] + lep);
      }
    }
  }
}

// ---------------------------------------------------------------------------
extern "C" void kernel_launch(void* const* d_in, const int* in_sizes, int n_in,
                              void* d_out, int out_size, void* d_ws, size_t ws_size,
                              hipStream_t stream) {
  const float* fmap     = (const float*)d_in[0];
  const float* w_qk     = (const float*)d_in[1];
  const float* w_v      = (const float*)d_in[2];
  const float* w_v_vert = (const float*)d_in[3];
  const float* w_proj   = (const float*)d_in[5];
  float* out = (float*)d_out;

  ushort_t* XT   = (ushort_t*)d_ws;                       // [8][4096][512]
  ushort_t* qkT  = XT + (size_t)8 * NPIX * 512;           // [8][4096][1024] pix-major
  ushort_t* vbuf = qkT + (size_t)8 * NPIX * 1024;         // [8][768][4096] ch-major
  ushort_t* attT = vbuf + (size_t)8 * 768 * NPIX;         // [8][4096][512]
  ushort_t* WQKV = attT + (size_t)8 * NPIX * 512;         // [1792][512]
  ushort_t* WPb  = WQKV + (size_t)1792 * 512;             // [512][512]

  dim3 blk(256);
  prep_w<<<1024, blk, 0, stream>>>(w_qk, w_v, w_proj, WQKV, WPb);
  lepe_w<<<256, blk, 0, stream>>>(w_v_vert, w_v, WQKV + (size_t)1536 * 512);
  transpose_cast<<<dim3(64, 8, 8), blk, 0, stream>>>(fmap, XT);
  // QKV GEMM: 128x256 tile (r16)
  gemm_qkv<<<dim3(16, 14, 8), blk, 0, stream>>>(WQKV, XT, qkT, vbuf);
  attn_mfma<<<dim3(8, 128, 2), blk, 0, stream>>>(qkT, vbuf, attT);
  // proj GEMM: 128x256 tile -> 512 blocks = exactly one full dispatch round
  gemm_proj<<<dim3(16, 4, 8), blk, 0, stream>>>(WPb, attT, out, fmap);
}

// Round 18
// 218.637 us; speedup vs baseline: 1.0476x; 1.0476x over previous
//
#include <hip/hip_runtime.h>
#include <hip/hip_bf16.h>

#define NPIX 4096
#define SCALE_L2E 0.18033688f   // 0.125 * log2(e); folded into Wq cast

typedef unsigned short ushort_t;
typedef __attribute__((ext_vector_type(8))) short bf16x8;
typedef __attribute__((ext_vector_type(4))) float f32x4;
typedef __attribute__((ext_vector_type(8))) unsigned short us8;

__device__ __forceinline__ float bf2f(ushort_t u) {
  union { unsigned int i; float f; } v; v.i = ((unsigned int)u) << 16; return v.f;
}
__device__ __forceinline__ ushort_t f2bf(float f) {
  union { float f; unsigned int i; } v; v.f = f;
  unsigned int r = v.i + 0x7fffu + ((v.i >> 16) & 1u);
  return (ushort_t)(r >> 16);
}
__device__ __forceinline__ unsigned int cvtpk(float lo, float hi) {
  unsigned int r;
  asm volatile("v_cvt_pk_bf16_f32 %0, %1, %2" : "=v"(r) : "v"(lo), "v"(hi));
  return r;
}

__device__ __forceinline__ void gload16(const void* g, void* l) {
  __builtin_amdgcn_global_load_lds(
      (const __attribute__((address_space(1))) void*)g,
      (__attribute__((address_space(3))) void*)l, 16, 0, 0);
}

#define VMW(N) asm volatile("s_waitcnt vmcnt(" #N ")" ::: "memory")
#define BARRS do { __builtin_amdgcn_s_barrier(); \
                   __builtin_amdgcn_sched_barrier(0); } while (0)

// ---------------------------------------------------------------------------
// Fused weight prep: 4 segments of 512x512 f32 -> bf16.
// ---------------------------------------------------------------------------
__global__ __launch_bounds__(256) void prep_w(const float* __restrict__ wqk,
                                              const float* __restrict__ wv,
                                              const float* __restrict__ wproj,
                                              ushort_t* __restrict__ WQKV,
                                              ushort_t* __restrict__ WPb) {
  const int i = (blockIdx.x * 256 + threadIdx.x) * 4;
  const int seg = i >> 18, off = i & 262143;
  const float* src;
  ushort_t* dst;
  float sc = 1.0f;
  if (seg == 0)      { src = wqk;          dst = WQKV;               sc = SCALE_L2E; }
  else if (seg == 1) { src = wqk + 262144; dst = WQKV + 262144; }
  else if (seg == 2) { src = wv;           dst = WQKV + 2 * 262144; }
  else               { src = wproj;        dst = WPb; }
  const float4 v = *(const float4*)&src[off];
  ushort4 o = make_ushort4(f2bf(v.x * sc), f2bf(v.y * sc),
                           f2bf(v.z * sc), f2bf(v.w * sc));
  *(ushort4*)&dst[off] = o;
}

// ---------------------------------------------------------------------------
// W_lepe[i][j] = sum_c w_v_vert[i][c] * w_v[256+c][j]   (256x512, bf16 out)
// ---------------------------------------------------------------------------
__global__ __launch_bounds__(256) void lepe_w(const float* __restrict__ wvv,
                                              const float* __restrict__ wv,
                                              ushort_t* __restrict__ out) {
  const int i = blockIdx.x, tid = threadIdx.x;
  float a0 = 0.f, a1 = 0.f;
  for (int c = 0; c < 256; ++c) {
    const float wc = wvv[i * 256 + c];
    a0 = fmaf(wc, wv[(size_t)(256 + c) * 512 + tid], a0);
    a1 = fmaf(wc, wv[(size_t)(256 + c) * 512 + 256 + tid], a1);
  }
  out[(size_t)i * 512 + tid] = f2bf(a0);
  out[(size_t)i * 512 + 256 + tid] = f2bf(a1);
}

// ---------------------------------------------------------------------------
// fmap [b][512][4096] f32 -> XT [b][4096][512] bf16 (float4 reads).
// ---------------------------------------------------------------------------
__global__ __launch_bounds__(256) void transpose_cast(const float* __restrict__ fmap,
                                                      ushort_t* __restrict__ XT) {
  const int b = blockIdx.z, p0 = blockIdx.x * 64, c0 = blockIdx.y * 64;
  const int tid = threadIdx.x;
  __shared__ float t[64][65];
  const float* src = fmap + ((size_t)b * 512 + c0) * NPIX + p0;
  const int cr = tid >> 4;
  const int p4 = (tid & 15) * 4;
  #pragma unroll
  for (int i = 0; i < 4; ++i) {
    const int c = i * 16 + cr;
    const float4 v = *(const float4*)&src[(size_t)c * NPIX + p4];
    t[c][p4 + 0] = v.x; t[c][p4 + 1] = v.y;
    t[c][p4 + 2] = v.z; t[c][p4 + 3] = v.w;
  }
  __syncthreads();
  const int pw = tid >> 2, cwb = (tid & 3) * 16;
  us8 o0, o1;
  #pragma unroll
  for (int i = 0; i < 8; ++i) o0[i] = f2bf(t[cwb + i][pw]);
  #pragma unroll
  for (int i = 0; i < 8; ++i) o1[i] = f2bf(t[cwb + 8 + i][pw]);
  ushort_t* dst = XT + ((size_t)b * NPIX + p0 + pw) * 512 + c0 + cwb;
  *(us8*)&dst[0] = o0;
  *(us8*)&dst[8] = o1;
}

// ---------------------------------------------------------------------------
// 128x128-tile GEMM, BK=32, 4 waves, 3-buffer LDS rotation (48 KB ->
// 3 blocks/CU), counted vmcnt (never 0 in loop), one barrier per K-tile.
// Best-measured configuration (r14, 218.9 us total).
// mode 0: QKV epilogue (rows<1024 -> qkT pix-major; >=1024 -> vbuf ch-major)
// mode 1: f32 + residual epilogue (proj).
// ---------------------------------------------------------------------------
__global__ __launch_bounds__(256) void gemm128(
    const ushort_t* __restrict__ A, const ushort_t* __restrict__ B,
    ushort_t* __restrict__ qkT, ushort_t* __restrict__ vbuf,
    float* __restrict__ outF, const float* __restrict__ Res, int mode)
{
  const int b = blockIdx.z;
  const int p0 = blockIdx.x * 128;
  const int o0 = blockIdx.y * 128;
  const int tid = threadIdx.x;
  const int lane = tid & 63, w = tid >> 6;
  const int wrow = (w >> 1) * 64, wcol = (w & 1) * 64;
  const int g = lane >> 4, q16 = lane & 15;

  __shared__ __attribute__((aligned(16))) ushort_t lds[3 * 8192];  // 48 KB

  const ushort_t* Bb = B + (size_t)b * NPIX * 512;

  f32x4 acc[4][4];
  #pragma unroll
  for (int m = 0; m < 4; ++m)
    #pragma unroll
    for (int n = 0; n < 4; ++n) acc[m][n] = (f32x4){0.f, 0.f, 0.f, 0.f};

  auto Ap = [&](int buf) { return lds + buf * 8192; };
  auto Bp = [&](int buf) { return lds + buf * 8192 + 4096; };

  auto stage = [&](int buf, int kb) {
    #pragma unroll
    for (int i = 0; i < 2; ++i) {
      const int r = w * 32 + i * 16 + (lane >> 2);
      const int cs = (lane & 3) ^ ((r >> 1) & 3);
      gload16(&A[(size_t)(o0 + r) * 512 + kb + cs * 8], Ap(buf) + (w * 32 + i * 16) * 32);
      gload16(&Bb[(size_t)(p0 + r) * 512 + kb + cs * 8], Bp(buf) + (w * 32 + i * 16) * 32);
    }
  };

  stage(0, 0);
  stage(1, 32);
  VMW(4);
  BARRS;

  #pragma unroll
  for (int kt = 0; kt < 16; ++kt) {
    const int c = kt % 3;
    if (kt < 14) stage((kt + 2) % 3, (kt + 2) * 32);
    bf16x8 af[4], bfr[4];
    #pragma unroll
    for (int m = 0; m < 4; ++m) {
      const int rr = wrow + m * 16 + q16;
      af[m] = *(const bf16x8*)&Ap(c)[rr * 32 + (g ^ ((rr >> 1) & 3)) * 8];
    }
    #pragma unroll
    for (int n = 0; n < 4; ++n) {
      const int rr = wcol + n * 16 + q16;
      bfr[n] = *(const bf16x8*)&Bp(c)[rr * 32 + (g ^ ((rr >> 1) & 3)) * 8];
    }
    __builtin_amdgcn_s_setprio(1);
    #pragma unroll
    for (int m = 0; m < 4; ++m)
      #pragma unroll
      for (int n = 0; n < 4; ++n)
        acc[m][n] = __builtin_amdgcn_mfma_f32_16x16x32_bf16(af[m], bfr[n], acc[m][n], 0, 0, 0);
    __builtin_amdgcn_s_setprio(0);
    if (kt < 14) { VMW(4); BARRS; }
    else if (kt == 14) { VMW(0); BARRS; }
  }

  const int fr = lane & 15, fq = lane >> 4;
  if (mode == 0) {
    if (o0 < 1024) {
      ushort_t* CT = qkT + (size_t)b * NPIX * 1024;
      #pragma unroll
      for (int m = 0; m < 4; ++m)
        #pragma unroll
        for (int n = 0; n < 4; ++n) {
          const int pix = p0 + wcol + n * 16 + fr;
          const int chb = o0 + wrow + m * 16 + fq * 4;
          ushort4 s4 = make_ushort4(f2bf(acc[m][n][0]), f2bf(acc[m][n][1]),
                                    f2bf(acc[m][n][2]), f2bf(acc[m][n][3]));
          *(ushort4*)&CT[(size_t)pix * 1024 + chb] = s4;
        }
    } else {
      ushort_t* C = vbuf + (size_t)b * 768 * NPIX;
      #pragma unroll
      for (int m = 0; m < 4; ++m)
        #pragma unroll
        for (int n = 0; n < 4; ++n) {
          const int col = p0 + wcol + n * 16 + fr;
          #pragma unroll
          for (int j = 0; j < 4; ++j) {
            const int row = o0 - 1024 + wrow + m * 16 + fq * 4 + j;
            C[(size_t)row * NPIX + col] = f2bf(acc[m][n][j]);
          }
        }
    }
  } else {
    float* C = outF + (size_t)b * 512 * NPIX;
    const float* R = Res + (size_t)b * 512 * NPIX;
    #pragma unroll
    for (int m = 0; m < 4; ++m)
      #pragma unroll
      for (int n = 0; n < 4; ++n) {
        const int col = p0 + wcol + n * 16 + fr;
        #pragma unroll
        for (int j = 0; j < 4; ++j) {
          const int row = o0 + wrow + m * 16 + fq * 4 + j;
          const size_t idx = (size_t)row * NPIX + col;
          C[idx] = acc[m][n][j] + R[idx];
        }
      }
  }
}

// ---------------------------------------------------------------------------
// MFMA flash attention (r14 version).
// ---------------------------------------------------------------------------
__global__ __launch_bounds__(256) void attn_mfma(const ushort_t* __restrict__ qkT,
                                                 const ushort_t* __restrict__ vbuf,
                                                 ushort_t* __restrict__ attT) {
  const int hh = blockIdx.x, wi = blockIdx.y, vert = blockIdx.z;
  const int b = wi >> 4, iw = wi & 15;
  const int tid = threadIdx.x;
  const int lane = tid & 63, w = tid >> 6;
  const int g = lane >> 4, q16 = lane & 15;
  const int qbase = w * 64;

  __shared__ __attribute__((aligned(16))) ushort_t K_lds[256 * 32];
  __shared__ __attribute__((aligned(16))) ushort_t VT_lds[32 * 256];
  __shared__ __attribute__((aligned(16))) ushort_t P_lds[4][64 * 40];

  const ushort_t* QKb = qkT + (size_t)b * NPIX * 1024;

  #pragma unroll
  for (int it = 0; it < 4; ++it) {
    const int j = w * 64 + it * 16 + (lane >> 2);
    const int cs = (lane & 3) ^ ((j >> 1) & 3);
    const int pj = vert ? iw * 256 + j : (j >> 2) * 64 + iw * 4 + (j & 3);
    gload16(&QKb[(size_t)pj * 1024 + 512 + hh * 32 + cs * 8],
            &K_lds[(w * 64 + it * 16) * 32]);
  }
  const ushort_t* Vg = vbuf + ((size_t)b * 768 + vert * 256 + hh * 32) * (size_t)NPIX;
  #pragma unroll
  for (int it = 0; it < 8; ++it) {
    const int d = it * 4 + w;
    const int jg = lane;
    const int pb = vert ? iw * 256 + jg * 4 : jg * 64 + iw * 4;
    const ushort4 v4 = *(const ushort4*)&Vg[(size_t)d * NPIX + pb];
    *(ushort4*)&VT_lds[d * 256 + (((jg >> 1) ^ d) << 3) + ((jg & 1) << 2)] = v4;
  }
  bf16x8 qf[4];
  #pragma unroll
  for (int qt = 0; qt < 4; ++qt) {
    const int q = qbase + qt * 16 + q16;
    const int qp = vert ? iw * 256 + q : (q >> 2) * 64 + iw * 4 + (q & 3);
    qf[qt] = *(const bf16x8*)&QKb[(size_t)qp * 1024 + hh * 32 + g * 8];
  }
  __syncthreads();

  float l[4] = {0.f, 0.f, 0.f, 0.f};
  f32x4 o[4][2];
  #pragma unroll
  for (int qt = 0; qt < 4; ++qt) {
    o[qt][0] = (f32x4){0.f, 0.f, 0.f, 0.f};
    o[qt][1] = (f32x4){0.f, 0.f, 0.f, 0.f};
  }

  const f32x4 zero4 = (f32x4){0.f, 0.f, 0.f, 0.f};
  const int kc = g ^ ((q16 >> 1) & 3);

  for (int jc = 0; jc < 8; ++jc) {
    bf16x8 kf0 = *(const bf16x8*)&K_lds[(jc * 32 + q16) * 32 + kc * 8];
    bf16x8 kf1 = *(const bf16x8*)&K_lds[(jc * 32 + 16 + q16) * 32 + kc * 8];
    f32x4 st[2][4];
    #pragma unroll
    for (int qt = 0; qt < 4; ++qt) {
      st[0][qt] = __builtin_amdgcn_mfma_f32_16x16x32_bf16(kf0, qf[qt], zero4, 0, 0, 0);
      st[1][qt] = __builtin_amdgcn_mfma_f32_16x16x32_bf16(kf1, qf[qt], zero4, 0, 0, 0);
    }
    #pragma unroll
    for (int qt = 0; qt < 4; ++qt) {
      const float p00 = exp2f(st[0][qt][0]), p01 = exp2f(st[0][qt][1]);
      const float p02 = exp2f(st[0][qt][2]), p03 = exp2f(st[0][qt][3]);
      const float p10 = exp2f(st[1][qt][0]), p11 = exp2f(st[1][qt][1]);
      const float p12 = exp2f(st[1][qt][2]), p13 = exp2f(st[1][qt][3]);
      float rs = ((p00 + p01) + (p02 + p03)) + ((p10 + p11) + (p12 + p13));
      rs += __shfl_xor(rs, 16);
      rs += __shfl_xor(rs, 32);
      l[qt] += rs;
      uint2 pk0, pk1;
      pk0.x = cvtpk(p00, p01); pk0.y = cvtpk(p02, p03);
      pk1.x = cvtpk(p10, p11); pk1.y = cvtpk(p12, p13);
      *(uint2*)&P_lds[w][(qt * 16 + q16) * 40 + g * 4]      = pk0;
      *(uint2*)&P_lds[w][(qt * 16 + q16) * 40 + 16 + g * 4] = pk1;
    }
    const int vc0 = (jc * 4 + g) ^ q16;
    const int vc1 = (jc * 4 + g) ^ (16 + q16);
    bf16x8 vf0 = *(const bf16x8*)&VT_lds[q16 * 256 + vc0 * 8];
    bf16x8 vf1 = *(const bf16x8*)&VT_lds[(16 + q16) * 256 + vc1 * 8];
    #pragma unroll
    for (int qt = 0; qt < 4; ++qt) {
      bf16x8 pf = *(const bf16x8*)&P_lds[w][(qt * 16 + q16) * 40 + g * 8];
      o[qt][0] = __builtin_amdgcn_mfma_f32_16x16x32_bf16(pf, vf0, o[qt][0], 0, 0, 0);
      o[qt][1] = __builtin_amdgcn_mfma_f32_16x16x32_bf16(pf, vf1, o[qt][1], 0, 0, 0);
    }
  }

  if (vert) {
    __syncthreads();
    const ushort_t* Lg = vbuf + ((size_t)b * 768 + 512 + hh * 32) * (size_t)NPIX;
    #pragma unroll
    for (int it = 0; it < 8; ++it) {
      const int d = it * 4 + w;
      const int jg = lane;
      const ushort4 l4 = *(const ushort4*)&Lg[(size_t)d * NPIX + iw * 256 + jg * 4];
      *(ushort4*)&K_lds[d * 256 + (((jg >> 1) ^ d) << 3) + ((jg & 1) << 2)] = l4;
    }
    __syncthreads();
  }

  const int ch = vert * 256 + hh * 32;
  #pragma unroll
  for (int qt = 0; qt < 4; ++qt) {
    const float linv = 1.f / l[qt];
    float li[4];
    #pragma unroll
    for (int jj = 0; jj < 4; ++jj) li[jj] = __shfl(linv, g * 4 + jj);
    #pragma unroll
    for (int dt = 0; dt < 2; ++dt) {
      const int d = dt * 16 + q16;
      #pragma unroll
      for (int jj = 0; jj < 4; ++jj) {
        const int q = qbase + qt * 16 + g * 4 + jj;
        const int sw = d * 256 + (((q >> 3) ^ d) << 3) + (q & 7);
        const float lep = vert ? bf2f(K_lds[sw]) : bf2f(VT_lds[sw]);
        const int pix = vert ? iw * 256 + q : (q >> 2) * 64 + iw * 4 + (q & 3);
        attT[((size_t)b * NPIX + pix) * 512 + ch + d] = f2bf(o[qt][dt][jj] * li[jj] + lep);
      }
    }
  }
}

// ---------------------------------------------------------------------------
extern "C" void kernel_launch(void* const* d_in, const int* in_sizes, int n_in,
                              void* d_out, int out_size, void* d_ws, size_t ws_size,
                              hipStream_t stream) {
  const float* fmap     = (const float*)d_in[0];
  const float* w_qk     = (const float*)d_in[1];
  const float* w_v      = (const float*)d_in[2];
  const float* w_v_vert = (const float*)d_in[3];
  const float* w_proj   = (const float*)d_in[5];
  float* out = (float*)d_out;

  ushort_t* XT   = (ushort_t*)d_ws;                       // [8][4096][512]
  ushort_t* qkT  = XT + (size_t)8 * NPIX * 512;           // [8][4096][1024] pix-major
  ushort_t* vbuf = qkT + (size_t)8 * NPIX * 1024;         // [8][768][4096] ch-major
  ushort_t* attT = vbuf + (size_t)8 * 768 * NPIX;         // [8][4096][512]
  ushort_t* WQKV = attT + (size_t)8 * NPIX * 512;         // [1792][512]
  ushort_t* WPb  = WQKV + (size_t)1792 * 512;             // [512][512]

  dim3 blk(256);
  prep_w<<<1024, blk, 0, stream>>>(w_qk, w_v, w_proj, WQKV, WPb);
  lepe_w<<<256, blk, 0, stream>>>(w_v_vert, w_v, WQKV + (size_t)1536 * 512);
  transpose_cast<<<dim3(64, 8, 8), blk, 0, stream>>>(fmap, XT);
  // QKV GEMM: 128^2 tiles, 3 blocks/CU, counted-vmcnt 3-buffer pipeline (r14 best)
  gemm128<<<dim3(32, 14, 8), blk, 0, stream>>>(
      WQKV, XT, qkT, vbuf, nullptr, nullptr, 0);
  attn_mfma<<<dim3(8, 128, 2), blk, 0, stream>>>(qkT, vbuf, attT);
  gemm128<<<dim3(32, 4, 8), blk, 0, stream>>>(
      WPb, attT, nullptr, nullptr, out, fmap, 1);
}